// Round 1
// baseline (438.974 us; speedup 1.0000x reference)
//
#include <hip/hip_runtime.h>
#include <hip/hip_bf16.h>
#include <stdint.h>

// Problem constants (B=16, N=512, D=768, H=6, Dh=128, layers=2)
#define BATCH 16
#define NSEQ  512
#define DMODEL 768
#define NHEAD 6
#define DHEAD 128
#define MROWS (BATCH * NSEQ)   // 8192

typedef __attribute__((ext_vector_type(8))) __bf16 bf16x8;
typedef __attribute__((ext_vector_type(4))) __bf16 bf16x4;
typedef __attribute__((ext_vector_type(4))) float  f32x4;
typedef __attribute__((ext_vector_type(4))) unsigned int u32x4;

__device__ inline float fast_tanh(float x) {
    float ax = fabsf(x);
    float e  = __expf(-2.f * ax);
    float t  = (1.f - e) / (1.f + e);
    return copysignf(t, x);
}

// ---------------- fp32 -> bf16 conversion (vectorized x4) ----------------
__global__ void cvt_bf16_kernel(const float* __restrict__ src,
                                __bf16* __restrict__ dst, int n4) {
    int i = blockIdx.x * blockDim.x + threadIdx.x;
    if (i < n4) {
        float4 v = reinterpret_cast<const float4*>(src)[i];
        bf16x4 o;
        o.x = (__bf16)v.x; o.y = (__bf16)v.y; o.z = (__bf16)v.z; o.w = (__bf16)v.w;
        reinterpret_cast<bf16x4*>(dst)[i] = o;
    }
}

// ---------------- bf16 MFMA GEMM:  C[m][n] = sum_k A[m][k] * Bm[n][k] -----
// A: [8192][768] bf16, Bm: [768][768] bf16 (W row-major (out,in) == B^T form)
// Tile 128x128, BK=32, 4 waves (2x2), each wave 64x64 = 4x4 frags of 16x16.
__global__ __launch_bounds__(256) void gemm_bt(const __bf16* __restrict__ A,
                                               const __bf16* __restrict__ Bm,
                                               __bf16* __restrict__ C) {
    __shared__ __bf16 As[128 * 32];
    __shared__ __bf16 Bs[128 * 32];
    const int tid  = threadIdx.x;
    const int lane = tid & 63;
    const int wave = tid >> 6;
    const int wm = wave >> 1, wn = wave & 1;
    const int m0 = blockIdx.y * 128;
    const int n0 = blockIdx.x * 128;

    f32x4 acc[4][4] = {};

    // staging: thread t covers elems [t*8, t*8+8) and [2048 + t*8, ...)
    const int e0   = tid * 8;
    const int row0 = e0 >> 5;        // /32 -> 0..63
    const int k0i  = e0 & 31;        // 0,8,16,24

    const int lr = lane & 15;
    const int kb = (lane >> 4) * 8;

    for (int kt = 0; kt < DMODEL; kt += 32) {
        u32x4 a0 = *reinterpret_cast<const u32x4*>(A  + (size_t)(m0 + row0)      * DMODEL + kt + k0i);
        u32x4 a1 = *reinterpret_cast<const u32x4*>(A  + (size_t)(m0 + row0 + 64) * DMODEL + kt + k0i);
        u32x4 b0 = *reinterpret_cast<const u32x4*>(Bm + (size_t)(n0 + row0)      * DMODEL + kt + k0i);
        u32x4 b1 = *reinterpret_cast<const u32x4*>(Bm + (size_t)(n0 + row0 + 64) * DMODEL + kt + k0i);
        __syncthreads();   // previous compute done before overwrite
        *reinterpret_cast<u32x4*>(&As[e0])        = a0;
        *reinterpret_cast<u32x4*>(&As[e0 + 2048]) = a1;
        *reinterpret_cast<u32x4*>(&Bs[e0])        = b0;
        *reinterpret_cast<u32x4*>(&Bs[e0 + 2048]) = b1;
        __syncthreads();

        bf16x8 af[4], bfv[4];
        #pragma unroll
        for (int i = 0; i < 4; i++)
            af[i] = *reinterpret_cast<const bf16x8*>(&As[(wm * 64 + i * 16 + lr) * 32 + kb]);
        #pragma unroll
        for (int j = 0; j < 4; j++)
            bfv[j] = *reinterpret_cast<const bf16x8*>(&Bs[(wn * 64 + j * 16 + lr) * 32 + kb]);
        #pragma unroll
        for (int i = 0; i < 4; i++)
            #pragma unroll
            for (int j = 0; j < 4; j++)
                acc[i][j] = __builtin_amdgcn_mfma_f32_16x16x32_bf16(af[i], bfv[j], acc[i][j], 0, 0, 0);
    }

    const int rg = (lane >> 4) * 4;
    #pragma unroll
    for (int i = 0; i < 4; i++) {
        #pragma unroll
        for (int j = 0; j < 4; j++) {
            #pragma unroll
            for (int r = 0; r < 4; r++) {
                int row = m0 + wm * 64 + i * 16 + rg + r;
                int col = n0 + wn * 64 + j * 16 + lr;
                C[(size_t)row * DMODEL + col] = (__bf16)acc[i][j][r];
            }
        }
    }
}

// ---------------- sq/sk:  sq[bn][h] = qk[bn,h,:] . Wa[h,:128]  ------------
__global__ void sqk_kernel(const __bf16* __restrict__ QK, const float* __restrict__ Wa,
                           float* __restrict__ sq, float* __restrict__ sk) {
    int idx = blockIdx.x * blockDim.x + threadIdx.x;   // 0..49151
    int bn = idx / NHEAD, h = idx % NHEAD;
    const __bf16* q  = QK + (size_t)bn * DMODEL + h * DHEAD;
    const float*  wq = Wa + h * (2 * DHEAD);
    float aq = 0.f, ak = 0.f;
    #pragma unroll 8
    for (int d = 0; d < DHEAD; d++) {
        float v = (float)q[d];
        aq += v * wq[d];
        ak += v * wq[DHEAD + d];
    }
    sq[idx] = aq;
    sk[idx] = ak;
}

// ---------------- fused score/softmax/PV/tanh/residual --------------------
// grid: (32 q-tiles, 6 heads, 16 batch); block 256.
__global__ __launch_bounds__(256) void attn_pv(const __bf16* __restrict__ QK,
                                               const float* __restrict__ sq,
                                               const float* __restrict__ sk,
                                               const float* __restrict__ pmask,
                                               const float* __restrict__ residual,
                                               float* __restrict__ out) {
    const int qt = blockIdx.x;   // 0..31
    const int h  = blockIdx.y;   // 0..5
    const int b  = blockIdx.z;   // 0..15
    const int q0 = qt * 16;
    __shared__ float w[16][512];
    __shared__ float sks[512];
    __shared__ float pmk[512];
    __shared__ float sqs[16], pmq[16], rden[16];
    const int tid = threadIdx.x;

    for (int k = tid; k < 512; k += 256) {
        sks[k] = sk[(size_t)(b * NSEQ + k) * NHEAD + h];
        pmk[k] = pmask[b * NSEQ + k];
    }
    if (tid < 16) {
        sqs[tid] = sq[(size_t)(b * NSEQ + q0 + tid) * NHEAD + h];
        pmq[tid] = pmask[b * NSEQ + q0 + tid];
    }
    __syncthreads();

    // scores -> exp(score)
    for (int idx = tid; idx < 16 * 512; idx += 256) {
        int q = idx >> 9, k = idx & 511;
        float s;
        if (pmq[q] * pmk[k] > 0.f) {
            s = fast_tanh(sqs[q] + sks[k]);
        } else {
            s = -1e-8f;
        }
        w[q][k] = __expf(s);
    }
    __syncthreads();

    // row sums -> reciprocal
    {
        int row = tid >> 4, c = tid & 15;
        float p = 0.f;
        #pragma unroll
        for (int j = 0; j < 32; j++) p += w[row][c + j * 16];
        #pragma unroll
        for (int off = 8; off; off >>= 1) p += __shfl_down(p, off);
        if (c == 0) rden[row] = 1.f / p;
    }
    __syncthreads();

    // PV: each thread owns (qg: 8 q-rows, d)
    const int d  = tid & 127;
    const int qg = tid >> 7;     // 0 or 1
    float acc[8] = {};
    const __bf16* V = QK + (size_t)b * NSEQ * DMODEL + (size_t)h * DHEAD + d;
    for (int k = 0; k < 512; k++) {
        float v = (float)V[(size_t)k * DMODEL];
        #pragma unroll
        for (int i = 0; i < 8; i++)
            acc[i] += w[qg * 8 + i][k] * v;
    }

    #pragma unroll
    for (int i = 0; i < 8; i++) {
        int q = qg * 8 + i;
        float hv = acc[i] * rden[q];
        float t  = fast_tanh(hv);
        size_t o = ((size_t)(b * NSEQ + q0 + q)) * DMODEL + (size_t)h * DHEAD + d;
        out[o] = residual[o] + t;
    }
}

extern "C" void kernel_launch(void* const* d_in, const int* in_sizes, int n_in,
                              void* d_out, int out_size, void* d_ws, size_t ws_size,
                              hipStream_t stream) {
    const float* pmask   = (const float*)d_in[0];
    const float* feature = (const float*)d_in[1];
    const float* W       = (const float*)d_in[2];
    const float* Wa      = (const float*)d_in[3];
    float* out = (float*)d_out;
    char* ws = (char*)d_ws;

    // workspace carve (all 256B aligned)
    __bf16* Abf  = (__bf16*)ws;                                   // 12,582,912 B
    __bf16* Wbf  = (__bf16*)(ws + 12582912);                      //  1,179,648 B
    __bf16* QKbf = (__bf16*)(ws + 12582912 + 1179648);            // 12,582,912 B
    float*  sq   = (float*)(ws + 12582912 + 1179648 + 12582912);  //    196,608 B
    float*  sk   = sq + MROWS * NHEAD;                            //    196,608 B

    const int featN4 = (MROWS * DMODEL) / 4;     // 1,572,864
    const int wN4    = (DMODEL * DMODEL) / 4;    //   147,456

    // W -> bf16 (once)
    hipLaunchKernelGGL(cvt_bf16_kernel, dim3((wN4 + 255) / 256), dim3(256), 0, stream,
                       W, Wbf, wN4);

    // ---- layer 1 ----
    hipLaunchKernelGGL(cvt_bf16_kernel, dim3((featN4 + 255) / 256), dim3(256), 0, stream,
                       feature, Abf, featN4);
    hipLaunchKernelGGL(gemm_bt, dim3(DMODEL / 128, MROWS / 128), dim3(256), 0, stream,
                       Abf, Wbf, QKbf);
    hipLaunchKernelGGL(sqk_kernel, dim3(MROWS * NHEAD / 256), dim3(256), 0, stream,
                       QKbf, Wa, sq, sk);
    hipLaunchKernelGGL(attn_pv, dim3(NSEQ / 16, NHEAD, BATCH), dim3(256), 0, stream,
                       QKbf, sq, sk, pmask, feature, out);

    // ---- layer 2 ---- (residual/input = layer-1 output in d_out; in-place safe)
    hipLaunchKernelGGL(cvt_bf16_kernel, dim3((featN4 + 255) / 256), dim3(256), 0, stream,
                       out, Abf, featN4);
    hipLaunchKernelGGL(gemm_bt, dim3(DMODEL / 128, MROWS / 128), dim3(256), 0, stream,
                       Abf, Wbf, QKbf);
    hipLaunchKernelGGL(sqk_kernel, dim3(MROWS * NHEAD / 256), dim3(256), 0, stream,
                       QKbf, Wa, sq, sk);
    hipLaunchKernelGGL(attn_pv, dim3(NSEQ / 16, NHEAD, BATCH), dim3(256), 0, stream,
                       QKbf, sq, sk, pmask, out, out);
}

// Round 2
// 194.126 us; speedup vs baseline: 2.2613x; 2.2613x over previous
//
#include <hip/hip_runtime.h>
#include <hip/hip_bf16.h>
#include <stdint.h>

// Problem constants (B=16, N=512, D=768, H=6, Dh=128, layers=2)
#define BATCH 16
#define NSEQ  512
#define DMODEL 768
#define NHEAD 6
#define DHEAD 128
#define MROWS (BATCH * NSEQ)   // 8192
#define QBLK  32
#define KTILE 64

typedef __attribute__((ext_vector_type(8))) __bf16 bf16x8;
typedef __attribute__((ext_vector_type(4))) __bf16 bf16x4;
typedef __attribute__((ext_vector_type(4))) float  f32x4;
typedef __attribute__((ext_vector_type(4))) unsigned int u32x4;
typedef __attribute__((ext_vector_type(8))) unsigned short u16x8;

__device__ inline float fast_tanh(float x) {
    float ax = fabsf(x);
    float e  = __expf(-2.f * ax);
    float t  = (1.f - e) / (1.f + e);
    return copysignf(t, x);
}

// ---------------- fp32 -> bf16 conversion (vectorized x4) ----------------
__global__ void cvt_bf16_kernel(const float* __restrict__ src,
                                __bf16* __restrict__ dst, int n4) {
    int i = blockIdx.x * blockDim.x + threadIdx.x;
    if (i < n4) {
        float4 v = reinterpret_cast<const float4*>(src)[i];
        bf16x4 o;
        o.x = (__bf16)v.x; o.y = (__bf16)v.y; o.z = (__bf16)v.z; o.w = (__bf16)v.w;
        reinterpret_cast<bf16x4*>(dst)[i] = o;
    }
}

// ---------------- bf16 MFMA GEMM:  C[m][n] = sum_k A[m][k] * Bm[n][k] -----
__global__ __launch_bounds__(256) void gemm_bt(const __bf16* __restrict__ A,
                                               const __bf16* __restrict__ Bm,
                                               __bf16* __restrict__ C) {
    __shared__ __bf16 As[128 * 32];
    __shared__ __bf16 Bs[128 * 32];
    const int tid  = threadIdx.x;
    const int lane = tid & 63;
    const int wave = tid >> 6;
    const int wm = wave >> 1, wn = wave & 1;
    const int m0 = blockIdx.y * 128;
    const int n0 = blockIdx.x * 128;

    f32x4 acc[4][4] = {};

    const int e0   = tid * 8;
    const int row0 = e0 >> 5;
    const int k0i  = e0 & 31;

    const int lr = lane & 15;
    const int kb = (lane >> 4) * 8;

    for (int kt = 0; kt < DMODEL; kt += 32) {
        u32x4 a0 = *reinterpret_cast<const u32x4*>(A  + (size_t)(m0 + row0)      * DMODEL + kt + k0i);
        u32x4 a1 = *reinterpret_cast<const u32x4*>(A  + (size_t)(m0 + row0 + 64) * DMODEL + kt + k0i);
        u32x4 b0 = *reinterpret_cast<const u32x4*>(Bm + (size_t)(n0 + row0)      * DMODEL + kt + k0i);
        u32x4 b1 = *reinterpret_cast<const u32x4*>(Bm + (size_t)(n0 + row0 + 64) * DMODEL + kt + k0i);
        __syncthreads();
        *reinterpret_cast<u32x4*>(&As[e0])        = a0;
        *reinterpret_cast<u32x4*>(&As[e0 + 2048]) = a1;
        *reinterpret_cast<u32x4*>(&Bs[e0])        = b0;
        *reinterpret_cast<u32x4*>(&Bs[e0 + 2048]) = b1;
        __syncthreads();

        bf16x8 af[4], bfv[4];
        #pragma unroll
        for (int i = 0; i < 4; i++)
            af[i] = *reinterpret_cast<const bf16x8*>(&As[(wm * 64 + i * 16 + lr) * 32 + kb]);
        #pragma unroll
        for (int j = 0; j < 4; j++)
            bfv[j] = *reinterpret_cast<const bf16x8*>(&Bs[(wn * 64 + j * 16 + lr) * 32 + kb]);
        #pragma unroll
        for (int i = 0; i < 4; i++)
            #pragma unroll
            for (int j = 0; j < 4; j++)
                acc[i][j] = __builtin_amdgcn_mfma_f32_16x16x32_bf16(af[i], bfv[j], acc[i][j], 0, 0, 0);
    }

    const int rg = (lane >> 4) * 4;
    #pragma unroll
    for (int i = 0; i < 4; i++) {
        #pragma unroll
        for (int j = 0; j < 4; j++) {
            #pragma unroll
            for (int r = 0; r < 4; r++) {
                int row = m0 + wm * 64 + i * 16 + rg + r;
                int col = n0 + wn * 64 + j * 16 + lr;
                C[(size_t)row * DMODEL + col] = (__bf16)acc[i][j][r];
            }
        }
    }
}

// ---------------- sq/sk ----------------------------------------------------
__global__ void sqk_kernel(const __bf16* __restrict__ QK, const float* __restrict__ Wa,
                           float* __restrict__ sq, float* __restrict__ sk) {
    int idx = blockIdx.x * blockDim.x + threadIdx.x;
    int bn = idx / NHEAD, h = idx % NHEAD;
    const __bf16* q  = QK + (size_t)bn * DMODEL + h * DHEAD;
    const float*  wq = Wa + h * (2 * DHEAD);
    float aq = 0.f, ak = 0.f;
    #pragma unroll 8
    for (int d = 0; d < DHEAD; d++) {
        float v = (float)q[d];
        aq += v * wq[d];
        ak += v * wq[DHEAD + d];
    }
    sq[idx] = aq;
    sk[idx] = ak;
}

// ---------------- fused score/softmax/MFMA-PV/tanh/residual ----------------
// grid: (NSEQ/QBLK=16, 6 heads, 16 batch); block 256 (4 waves).
// wave w: q rows (w&1)*16, d cols (w>>1)*64.
__global__ __launch_bounds__(256) void attn_pv(const __bf16* __restrict__ QK,
                                               const float* __restrict__ sq,
                                               const float* __restrict__ sk,
                                               const float* __restrict__ pmask,
                                               const float* __restrict__ residual,
                                               float* __restrict__ out) {
    const int qt = blockIdx.x;
    const int h  = blockIdx.y;
    const int b  = blockIdx.z;
    const int q0 = qt * QBLK;
    __shared__ __bf16 w[QBLK][520];          // padded: +8 -> conflict-free A reads
    __shared__ __bf16 Vt[DHEAD][KTILE];      // transposed V tile, XOR-swizzled
    __shared__ float sks[NSEQ], pmk[NSEQ];
    __shared__ float sqs[QBLK], pmq[QBLK], rden[QBLK];
    const int tid  = threadIdx.x;
    const int lane = tid & 63;
    const int wave = tid >> 6;

    for (int k = tid; k < NSEQ; k += 256) {
        sks[k] = sk[(size_t)(b * NSEQ + k) * NHEAD + h];
        pmk[k] = pmask[b * NSEQ + k];
    }
    if (tid < QBLK) {
        sqs[tid] = sq[(size_t)(b * NSEQ + q0 + tid) * NHEAD + h];
        pmq[tid] = pmask[b * NSEQ + q0 + tid];
    }
    __syncthreads();

    // ---- phase 1: w[q][k] = exp(score) in bf16 ----
    #pragma unroll
    for (int g = 0; g < 8; g++) {
        int grp = tid + g * 256;             // 0..2047
        int q   = grp >> 6;                  // 64 groups-of-8 per row
        int k0  = (grp & 63) * 8;
        float sqv = sqs[q], pq = pmq[q];
        bf16x8 wv;
        #pragma unroll
        for (int j = 0; j < 8; j++) {
            int k = k0 + j;
            float s = (pq * pmk[k] > 0.f) ? fast_tanh(sqv + sks[k]) : -1e-8f;
            wv[j] = (__bf16)__expf(s);
        }
        *reinterpret_cast<bf16x8*>(&w[q][k0]) = wv;
    }
    __syncthreads();

    // ---- row sums -> rden ----
    {
        int row = tid >> 3, c = tid & 7;
        float p = 0.f;
        #pragma unroll
        for (int j = 0; j < 8; j++) {
            bf16x8 v = *reinterpret_cast<const bf16x8*>(&w[row][c * 8 + j * 64]);
            #pragma unroll
            for (int e = 0; e < 8; e++) p += (float)v[e];
        }
        #pragma unroll
        for (int off = 4; off; off >>= 1) p += __shfl_down(p, off);
        if (c == 0) rden[row] = 1.f / p;
    }

    // ---- phase 2: PV via MFMA, 8 tiles of KTILE=64 ----
    // staging: thread handles (k=2*(tid>>4), d0=(tid&15)*8) and (k+32, d0)
    const int sd0 = (tid & 15) * 8;
    const int sk0 = (tid >> 4) * 2;
    const __bf16* Vbase = QK + (size_t)b * NSEQ * DMODEL + (size_t)h * DHEAD + sd0;

    u16x8 ra0, ra1, rb0, rb1;
    #define LOADS(t) do { \
        const __bf16* p0 = Vbase + (size_t)((t) * KTILE + sk0) * DMODEL; \
        ra0 = *reinterpret_cast<const u16x8*>(p0); \
        ra1 = *reinterpret_cast<const u16x8*>(p0 + DMODEL); \
        rb0 = *reinterpret_cast<const u16x8*>(p0 + 32 * DMODEL); \
        rb1 = *reinterpret_cast<const u16x8*>(p0 + 33 * DMODEL); \
    } while (0)

    #define WRITE_PAIR(lo, hi, kk) do { \
        _Pragma("unroll") \
        for (int j = 0; j < 8; j++) { \
            int d = sd0 + j; \
            int swz = (d & 7) ^ ((d >> 3) & 7); \
            unsigned int pk = (unsigned int)(lo)[j] | ((unsigned int)(hi)[j] << 16); \
            *reinterpret_cast<unsigned int*>( \
                reinterpret_cast<char*>(&Vt[0][0]) + d * (KTILE * 2) + (((kk) ^ (swz << 3)) * 2)) = pk; \
        } \
    } while (0)

    const int wq0 = (wave & 1) * 16;
    const int wd0 = (wave >> 1) * 64;
    const int lr  = lane & 15;
    const int lg  = lane >> 4;

    f32x4 acc[4] = {};

    LOADS(0);
    WRITE_PAIR(ra0, ra1, sk0);
    WRITE_PAIR(rb0, rb1, sk0 + 32);
    __syncthreads();

    for (int t = 0; t < 8; t++) {
        if (t < 7) LOADS(t + 1);
        #pragma unroll
        for (int ks = 0; ks < 2; ks++) {
            bf16x8 af = *reinterpret_cast<const bf16x8*>(&w[wq0 + lr][t * 64 + ks * 32 + lg * 8]);
            #pragma unroll
            for (int n = 0; n < 4; n++) {
                int d   = wd0 + n * 16 + lr;
                int kb  = ks * 4 + lg;
                int swz = (d & 7) ^ ((d >> 3) & 7);
                bf16x8 bf = *reinterpret_cast<const bf16x8*>(&Vt[d][(kb ^ swz) * 8]);
                acc[n] = __builtin_amdgcn_mfma_f32_16x16x32_bf16(af, bf, acc[n], 0, 0, 0);
            }
        }
        __syncthreads();
        if (t < 7) {
            WRITE_PAIR(ra0, ra1, sk0);
            WRITE_PAIR(rb0, rb1, sk0 + 32);
            __syncthreads();
        }
    }

    // ---- epilogue: normalize, tanh, +residual ----
    #pragma unroll
    for (int n = 0; n < 4; n++) {
        #pragma unroll
        for (int r = 0; r < 4; r++) {
            int ql = wq0 + lg * 4 + r;
            int d  = wd0 + n * 16 + lr;
            float hv = acc[n][r] * rden[ql];
            float tv = fast_tanh(hv);
            size_t o = ((size_t)(b * NSEQ + q0 + ql)) * DMODEL + (size_t)h * DHEAD + d;
            out[o] = residual[o] + tv;
        }
    }
    #undef LOADS
    #undef WRITE_PAIR
}

extern "C" void kernel_launch(void* const* d_in, const int* in_sizes, int n_in,
                              void* d_out, int out_size, void* d_ws, size_t ws_size,
                              hipStream_t stream) {
    const float* pmask   = (const float*)d_in[0];
    const float* feature = (const float*)d_in[1];
    const float* W       = (const float*)d_in[2];
    const float* Wa      = (const float*)d_in[3];
    float* out = (float*)d_out;
    char* ws = (char*)d_ws;

    __bf16* Abf  = (__bf16*)ws;
    __bf16* Wbf  = (__bf16*)(ws + 12582912);
    __bf16* QKbf = (__bf16*)(ws + 12582912 + 1179648);
    float*  sq   = (float*)(ws + 12582912 + 1179648 + 12582912);
    float*  sk   = sq + MROWS * NHEAD;

    const int featN4 = (MROWS * DMODEL) / 4;
    const int wN4    = (DMODEL * DMODEL) / 4;

    hipLaunchKernelGGL(cvt_bf16_kernel, dim3((wN4 + 255) / 256), dim3(256), 0, stream,
                       W, Wbf, wN4);

    // ---- layer 1 ----
    hipLaunchKernelGGL(cvt_bf16_kernel, dim3((featN4 + 255) / 256), dim3(256), 0, stream,
                       feature, Abf, featN4);
    hipLaunchKernelGGL(gemm_bt, dim3(DMODEL / 128, MROWS / 128), dim3(256), 0, stream,
                       Abf, Wbf, QKbf);
    hipLaunchKernelGGL(sqk_kernel, dim3(MROWS * NHEAD / 256), dim3(256), 0, stream,
                       QKbf, Wa, sq, sk);
    hipLaunchKernelGGL(attn_pv, dim3(NSEQ / QBLK, NHEAD, BATCH), dim3(256), 0, stream,
                       QKbf, sq, sk, pmask, feature, out);

    // ---- layer 2 ----
    hipLaunchKernelGGL(cvt_bf16_kernel, dim3((featN4 + 255) / 256), dim3(256), 0, stream,
                       out, Abf, featN4);
    hipLaunchKernelGGL(gemm_bt, dim3(DMODEL / 128, MROWS / 128), dim3(256), 0, stream,
                       Abf, Wbf, QKbf);
    hipLaunchKernelGGL(sqk_kernel, dim3(MROWS * NHEAD / 256), dim3(256), 0, stream,
                       QKbf, Wa, sq, sk);
    hipLaunchKernelGGL(attn_pv, dim3(NSEQ / QBLK, NHEAD, BATCH), dim3(256), 0, stream,
                       QKbf, sq, sk, pmask, out, out);
}

// Round 3
// 150.749 us; speedup vs baseline: 2.9119x; 1.2877x over previous
//
#include <hip/hip_runtime.h>
#include <hip/hip_bf16.h>
#include <stdint.h>

// Problem constants (B=16, N=512, D=768, H=6, Dh=128, layers=2)
#define BATCH 16
#define NSEQ  512
#define DMODEL 768
#define NHEAD 6
#define DHEAD 128
#define MROWS (BATCH * NSEQ)   // 8192
#define QBLK  32
#define KTILE 64

typedef __attribute__((ext_vector_type(8))) __bf16 bf16x8;
typedef __attribute__((ext_vector_type(4))) __bf16 bf16x4;
typedef __attribute__((ext_vector_type(4))) float  f32x4;
typedef __attribute__((ext_vector_type(4))) unsigned int u32x4;
typedef __attribute__((ext_vector_type(8))) unsigned short u16x8;

__device__ inline float fast_tanh(float x) {
    float ax = fabsf(x);
    float e  = __expf(-2.f * ax);
    float t  = (1.f - e) * __builtin_amdgcn_rcpf(1.f + e);
    return copysignf(t, x);
}

__device__ inline float b2f(unsigned short u) {
    union { unsigned int i; float f; } c;
    c.i = ((unsigned int)u) << 16;
    return c.f;
}

#define GLD16(gp, lp) __builtin_amdgcn_global_load_lds( \
    (const __attribute__((address_space(1))) unsigned int*)(gp), \
    (__attribute__((address_space(3))) unsigned int*)(lp), 16, 0, 0)

// ---------------- fp32 -> bf16 conversion (vectorized x4) ----------------
__global__ void cvt_bf16_kernel(const float* __restrict__ src,
                                __bf16* __restrict__ dst, int n4) {
    int i = blockIdx.x * blockDim.x + threadIdx.x;
    if (i < n4) {
        float4 v = reinterpret_cast<const float4*>(src)[i];
        bf16x4 o;
        o.x = (__bf16)v.x; o.y = (__bf16)v.y; o.z = (__bf16)v.z; o.w = (__bf16)v.w;
        reinterpret_cast<bf16x4*>(dst)[i] = o;
    }
}

// ---------------- bf16 MFMA GEMM:  C[m][n] = sum_k A[m][k] * Bm[n][k] -----
// global_load_lds staging (m97 structure).
__global__ __launch_bounds__(256) void gemm_bt(const __bf16* __restrict__ A,
                                               const __bf16* __restrict__ Bm,
                                               __bf16* __restrict__ C) {
    __shared__ __bf16 As[128 * 32];
    __shared__ __bf16 Bs[128 * 32];
    const int tid  = threadIdx.x;
    const int lane = tid & 63;
    const int wave = tid >> 6;
    const int wm = wave >> 1, wn = wave & 1;
    const int m0 = blockIdx.y * 128;
    const int n0 = blockIdx.x * 128;

    f32x4 acc[4][4] = {};

    const int e0   = tid * 8;        // element offset; byte = tid*16 (wave-uniform base + lane*16)
    const int row0 = tid >> 2;       // 0..63
    const int k0i  = (tid & 3) * 8;  // 0,8,16,24

    const int lr = lane & 15;
    const int kb = (lane >> 4) * 8;

    for (int kt = 0; kt < DMODEL; kt += 32) {
        __syncthreads();   // previous MFMA reads done before DMA overwrite
        GLD16(A  + (size_t)(m0 + row0)      * DMODEL + kt + k0i, &As[e0]);
        GLD16(A  + (size_t)(m0 + row0 + 64) * DMODEL + kt + k0i, &As[e0 + 2048]);
        GLD16(Bm + (size_t)(n0 + row0)      * DMODEL + kt + k0i, &Bs[e0]);
        GLD16(Bm + (size_t)(n0 + row0 + 64) * DMODEL + kt + k0i, &Bs[e0 + 2048]);
        __syncthreads();   // drains vmcnt -> LDS ready

        bf16x8 af[4], bfv[4];
        #pragma unroll
        for (int i = 0; i < 4; i++)
            af[i] = *reinterpret_cast<const bf16x8*>(&As[(wm * 64 + i * 16 + lr) * 32 + kb]);
        #pragma unroll
        for (int j = 0; j < 4; j++)
            bfv[j] = *reinterpret_cast<const bf16x8*>(&Bs[(wn * 64 + j * 16 + lr) * 32 + kb]);
        #pragma unroll
        for (int i = 0; i < 4; i++)
            #pragma unroll
            for (int j = 0; j < 4; j++)
                acc[i][j] = __builtin_amdgcn_mfma_f32_16x16x32_bf16(af[i], bfv[j], acc[i][j], 0, 0, 0);
    }

    const int rg = (lane >> 4) * 4;
    #pragma unroll
    for (int i = 0; i < 4; i++) {
        #pragma unroll
        for (int j = 0; j < 4; j++) {
            #pragma unroll
            for (int r = 0; r < 4; r++) {
                int row = m0 + wm * 64 + i * 16 + rg + r;
                int col = n0 + wn * 64 + j * 16 + lr;
                C[(size_t)row * DMODEL + col] = (__bf16)acc[i][j][r];
            }
        }
    }
}

// ---------------- sq/sk (transposed [h][b*n] layout, vectorized loads) ----
__global__ void sqk_kernel(const __bf16* __restrict__ QK, const float* __restrict__ Wa,
                           float* __restrict__ sq_t, float* __restrict__ sk_t) {
    int idx = blockIdx.x * blockDim.x + threadIdx.x;   // 0..49151
    int h  = idx >> 13;      // 0..5
    int bn = idx & 8191;
    const __bf16* q  = QK + (size_t)bn * DMODEL + h * DHEAD;
    const float*  wq = Wa + h * (2 * DHEAD);
    float aq = 0.f, ak = 0.f;
    #pragma unroll
    for (int d0 = 0; d0 < DHEAD; d0 += 8) {
        u16x8 v = *reinterpret_cast<const u16x8*>(q + d0);
        #pragma unroll
        for (int j = 0; j < 8; j++) {
            float f = b2f(v[j]);
            aq += f * wq[d0 + j];
            ak += f * wq[DHEAD + d0 + j];
        }
    }
    sq_t[idx] = aq;   // layout: [h][b*512 + n]
    sk_t[idx] = ak;
}

// ---------------- fused score/softmax/MFMA-PV/tanh/residual ----------------
// flat grid 1536, XCD-chunked decode; block 256 (4 waves).
__global__ __launch_bounds__(256) void attn_pv(const __bf16* __restrict__ QK,
                                               const float* __restrict__ sq_t,
                                               const float* __restrict__ sk_t,
                                               const float* __restrict__ pmask,
                                               const float* __restrict__ residual,
                                               float* __restrict__ out) {
    const int wg  = blockIdx.x;
    const int nid = (wg & 7) * 192 + (wg >> 3);   // bijective: 1536 = 8*192
    const int qt = nid & 15;
    const int hb = nid >> 4;     // 0..95
    const int h  = hb % NHEAD;
    const int b  = hb / NHEAD;
    const int q0 = qt * QBLK;

    __shared__ __bf16 w[QBLK][520];           // attn weights (numerator), bf16
    __shared__ __bf16 Vt[2][DHEAD][KTILE];    // transposed V, double-buffered, XOR-swizzled
    __shared__ float sks[NSEQ], pmk[NSEQ];
    __shared__ float sqs[QBLK], pmq[QBLK], rden[QBLK];
    const int tid  = threadIdx.x;
    const int lane = tid & 63;
    const int wave = tid >> 6;

    for (int k = tid; k < NSEQ; k += 256) {
        sks[k] = sk_t[(size_t)(h * BATCH + b) * NSEQ + k];   // contiguous
        pmk[k] = pmask[b * NSEQ + k];
    }
    if (tid < QBLK) {
        sqs[tid] = sq_t[(size_t)(h * BATCH + b) * NSEQ + q0 + tid];
        pmq[tid] = pmask[b * NSEQ + q0 + tid];
    }
    __syncthreads();

    // ---- phase 1: w[q][k] = exp(score), vectorized LDS reads ----
    #pragma unroll
    for (int g = 0; g < 8; g++) {
        int grp = tid + g * 256;             // 0..2047
        int q   = grp >> 6;
        int k0  = (grp & 63) * 8;
        float sqv = sqs[q], pq = pmq[q];
        float4 ska = *reinterpret_cast<const float4*>(&sks[k0]);
        float4 skb = *reinterpret_cast<const float4*>(&sks[k0 + 4]);
        float4 pma = *reinterpret_cast<const float4*>(&pmk[k0]);
        float4 pmb = *reinterpret_cast<const float4*>(&pmk[k0 + 4]);
        float sarr[8] = {ska.x, ska.y, ska.z, ska.w, skb.x, skb.y, skb.z, skb.w};
        float parr[8] = {pma.x, pma.y, pma.z, pma.w, pmb.x, pmb.y, pmb.z, pmb.w};
        bf16x8 wv;
        #pragma unroll
        for (int j = 0; j < 8; j++) {
            float s = (pq * parr[j] > 0.f) ? fast_tanh(sqv + sarr[j]) : -1e-8f;
            wv[j] = (__bf16)__expf(s);
        }
        *reinterpret_cast<bf16x8*>(&w[q][k0]) = wv;
    }
    __syncthreads();

    // ---- row sums -> rden ----
    {
        int row = tid >> 3, c = tid & 7;
        float p = 0.f;
        #pragma unroll
        for (int j = 0; j < 8; j++) {
            bf16x8 v = *reinterpret_cast<const bf16x8*>(&w[row][c * 8 + j * 64]);
            #pragma unroll
            for (int e = 0; e < 8; e++) p += (float)v[e];
        }
        #pragma unroll
        for (int off = 4; off; off >>= 1) p += __shfl_down(p, off);
        if (c == 0) rden[row] = 1.f / p;
    }

    // ---- phase 2: PV via MFMA, 8 tiles of KTILE=64, double-buffered Vt ----
    // staging: thread covers k rows sk0..sk0+3 (4 consecutive), d cols sd0..sd0+7
    const int sd0 = (tid & 15) * 8;
    const int sk0 = (tid >> 4) * 4;     // 0..60
    const __bf16* Vbase = QK + (size_t)b * NSEQ * DMODEL + (size_t)h * DHEAD + sd0;

    u16x8 r0, r1, r2, r3;
    #define LOADS(t) do { \
        const __bf16* p = Vbase + (size_t)((t) * KTILE + sk0) * DMODEL; \
        r0 = *reinterpret_cast<const u16x8*>(p); \
        r1 = *reinterpret_cast<const u16x8*>(p + DMODEL); \
        r2 = *reinterpret_cast<const u16x8*>(p + 2 * DMODEL); \
        r3 = *reinterpret_cast<const u16x8*>(p + 3 * DMODEL); \
    } while (0)

    // Vt[buf][d][kcol]: kcol = k ^ (8*swz(d)), swz(d) = (d&7)^((d>>3)&7).
    // write 4 consecutive k per d as one b64.
    #define WRITEV(bufi) do { \
        _Pragma("unroll") \
        for (int j = 0; j < 8; j++) { \
            int d = sd0 + j; \
            int swz = j ^ (tid & 7); \
            unsigned long long pk = (unsigned long long)r0[j] \
                                  | ((unsigned long long)r1[j] << 16) \
                                  | ((unsigned long long)r2[j] << 32) \
                                  | ((unsigned long long)r3[j] << 48); \
            *reinterpret_cast<unsigned long long*>( \
                reinterpret_cast<char*>(&Vt[bufi][0][0]) + d * (KTILE * 2) + ((sk0 ^ (swz << 3)) * 2)) = pk; \
        } \
    } while (0)

    const int wq0 = (wave & 1) * 16;
    const int wd0 = (wave >> 1) * 64;
    const int lr  = lane & 15;
    const int lg  = lane >> 4;

    f32x4 acc[4] = {};

    LOADS(0);
    WRITEV(0);
    LOADS(1);
    __syncthreads();

    for (int t = 0; t < 8; t++) {
        const int buf = t & 1;
        #pragma unroll
        for (int ks = 0; ks < 2; ks++) {
            bf16x8 af = *reinterpret_cast<const bf16x8*>(&w[wq0 + lr][t * 64 + ks * 32 + lg * 8]);
            #pragma unroll
            for (int n = 0; n < 4; n++) {
                int d   = wd0 + n * 16 + lr;
                int kbk = ks * 4 + lg;
                int swz = (d & 7) ^ ((d >> 3) & 7);
                bf16x8 bv = *reinterpret_cast<const bf16x8*>(
                    reinterpret_cast<const char*>(&Vt[buf][0][0]) + d * (KTILE * 2) + ((kbk ^ swz) * 16));
                acc[n] = __builtin_amdgcn_mfma_f32_16x16x32_bf16(af, bv, acc[n], 0, 0, 0);
            }
        }
        if (t < 7) WRITEV(buf ^ 1);   // stage tile t+1 (regs hold it; vmcnt waited by compiler)
        if (t < 6) LOADS(t + 2);      // issue next loads; latency hidden under next MFMA phase
        __syncthreads();
    }

    // ---- epilogue: normalize, tanh, +residual ----
    #pragma unroll
    for (int n = 0; n < 4; n++) {
        #pragma unroll
        for (int r = 0; r < 4; r++) {
            int ql = wq0 + lg * 4 + r;
            int d  = wd0 + n * 16 + lr;
            float hv = acc[n][r] * rden[ql];
            float tv = fast_tanh(hv);
            size_t o = ((size_t)(b * NSEQ + q0 + ql)) * DMODEL + (size_t)h * DHEAD + d;
            out[o] = residual[o] + tv;
        }
    }
    #undef LOADS
    #undef WRITEV
}

extern "C" void kernel_launch(void* const* d_in, const int* in_sizes, int n_in,
                              void* d_out, int out_size, void* d_ws, size_t ws_size,
                              hipStream_t stream) {
    const float* pmask   = (const float*)d_in[0];
    const float* feature = (const float*)d_in[1];
    const float* W       = (const float*)d_in[2];
    const float* Wa      = (const float*)d_in[3];
    float* out = (float*)d_out;
    char* ws = (char*)d_ws;

    __bf16* Abf  = (__bf16*)ws;
    __bf16* Wbf  = (__bf16*)(ws + 12582912);
    __bf16* QKbf = (__bf16*)(ws + 12582912 + 1179648);
    float*  sq   = (float*)(ws + 12582912 + 1179648 + 12582912);
    float*  sk   = sq + MROWS * NHEAD;

    const int featN4 = (MROWS * DMODEL) / 4;
    const int wN4    = (DMODEL * DMODEL) / 4;

    hipLaunchKernelGGL(cvt_bf16_kernel, dim3((wN4 + 255) / 256), dim3(256), 0, stream,
                       W, Wbf, wN4);

    // ---- layer 1 ----
    hipLaunchKernelGGL(cvt_bf16_kernel, dim3((featN4 + 255) / 256), dim3(256), 0, stream,
                       feature, Abf, featN4);
    hipLaunchKernelGGL(gemm_bt, dim3(DMODEL / 128, MROWS / 128), dim3(256), 0, stream,
                       Abf, Wbf, QKbf);
    hipLaunchKernelGGL(sqk_kernel, dim3(MROWS * NHEAD / 256), dim3(256), 0, stream,
                       QKbf, Wa, sq, sk);
    hipLaunchKernelGGL(attn_pv, dim3(1536), dim3(256), 0, stream,
                       QKbf, sq, sk, pmask, feature, out);

    // ---- layer 2 ----
    hipLaunchKernelGGL(cvt_bf16_kernel, dim3((featN4 + 255) / 256), dim3(256), 0, stream,
                       out, Abf, featN4);
    hipLaunchKernelGGL(gemm_bt, dim3(DMODEL / 128, MROWS / 128), dim3(256), 0, stream,
                       Abf, Wbf, QKbf);
    hipLaunchKernelGGL(sqk_kernel, dim3(MROWS * NHEAD / 256), dim3(256), 0, stream,
                       QKbf, Wa, sq, sk);
    hipLaunchKernelGGL(attn_pv, dim3(1536), dim3(256), 0, stream,
                       QKbf, sq, sk, pmask, out, out);
}